// Round 8
// baseline (18.535 us; speedup 1.0000x reference)
//
#include <hip/hip_runtime.h>

// Fused quanvolution + FC + log_softmax via MFMA (gfx950).
// Multi-slab: each block processes NSLAB=2 slabs of 16 images (grid = B/32),
// amortizing per-block costs (B-frag gather, ramp) and pipelining: slab s+1's
// x loads are issued into registers during slab s's compute; wave0's softmax
// epilogue overlaps the other waves' next-slab trig phase.
//
// Phase A (per slab): lane-coalesced x float4 stream -> trig -> q (bf16) LDS.
//   za = cos(pa)cos(xa) + sin(pa)sin(xa)sin(xb)
//   zb = cos(pb)cos(xa)cos(xb) + sin(pb)sin(xb)
// even image rows -> (p0,p1); odd rows -> (p2,p3).
// q slot: ((y>>1)*14 + col/2)*4 + (y&1)*2 + (col&1)   [q-order K]
//
// Phase B: logits[16][10] = q[16][784] @ w[784][10], mfma_f32_16x16x32_bf16.
// Lane l: i16=l&15 (image/class), g=l>>4. A frag = q_lds[i16][kb*32+8g..+7]
// (ds_read_b128, stride 808). B frag = fc_w[class][k..k+7], gathered ONCE.
// kb = wv + 8I (25 kblocks over 8 waves). C frag (m89): col=i16, row=4g+reg.

typedef __attribute__((ext_vector_type(8))) short short8;
typedef __attribute__((ext_vector_type(4))) float f32x4;

constexpr int BLOCK = 512;            // 8 waves
constexpr int IMGS  = 16;             // images per slab
constexpr int NSLAB = 2;              // slabs per block
constexpr int S2    = 808;            // q_lds stride (bf16), 16B-multiple
constexpr int NIT   = 4;              // ceil(25 kblocks / 8 waves)

static __device__ __forceinline__ unsigned pkbf2(float lo, float hi) {
    unsigned r;
    asm("v_cvt_pk_bf16_f32 %0, %1, %2" : "=v"(r) : "v"(lo), "v"(hi));
    return r;                          // [15:0]=bf16(lo), [31:16]=bf16(hi)
}

__global__ __launch_bounds__(BLOCK, 4)
void quanv_mfma(const float* __restrict__ x,
                const float* __restrict__ vqc,
                const float* __restrict__ fc_w,
                const float* __restrict__ fc_b,
                const float* __restrict__ bias,
                float* __restrict__ out,
                int B)
{
    __shared__ __align__(16) unsigned short q_lds[IMGS * S2];   // 25856 B
    __shared__ float cpart[7 * 256];                             // 7168 B

    const int tid  = threadIdx.x;
    const int lane = tid & 63;
    const int wv   = tid >> 6;          // 0..7
    const int i16  = lane & 15;         // image (A row) / class (B col)
    const int g    = lane >> 4;         // k-subgroup
    const float4* __restrict__ xf4 = reinterpret_cast<const float4*>(x);

    // slab image bases (clamped for safety; exact fit in practice)
    int ib0 = (blockIdx.x * NSLAB + 0) * IMGS;
    int ib1 = (blockIdx.x * NSLAB + 1) * IMGS;
    if (ib0 > B - IMGS) ib0 = B - IMGS;
    if (ib1 > B - IMGS) ib1 = B - IMGS;
    const long ub0 = (long)ib0 * 196;   // float4-unit base of slab
    const long ub1 = (long)ib1 * 196;

    // ---- issue slab0's 7 x-loads FIRST: start the HBM stream at cycle 0 ----
    // r[6] uses (tid&63) so the address is in-bounds for every thread;
    // only tid<64 consumes it.
    float4 r[7];
    #pragma unroll
    for (int t = 0; t < 6; ++t) r[t] = xf4[ub0 + t * BLOCK + tid];
    r[6] = xf4[ub0 + 6 * BLOCK + (tid & 63)];

    // ---- circuit params (overlap load latency) ----
    float S0, C0, S1, C1, S2p, C2p, S3, C3;
    __sincosf(vqc[0], &S0, &C0);
    __sincosf(vqc[1], &S1, &C1);
    __sincosf(vqc[2], &S2p, &C2p);
    __sincosf(vqc[3], &S3, &C3);

    // zero pad region k = 784..807 (12 u32 per image) — persists (cpart separate)
    if (tid < 192) {
        const unsigned im = (unsigned)tid / 12u;
        const unsigned o  = (unsigned)tid - 12u * im;
        *reinterpret_cast<unsigned*>(&q_lds[im * S2 + 784 + 2 * o]) = 0u;
    }

    // ---- B fragments (fc_w, L2-hot) gathered ONCE, reused for both slabs ----
    const int ncl = (i16 < 10) ? i16 : 9;
    const float* __restrict__ wrow = fc_w + ncl * 784;
    short8 bf[NIT];
    #pragma unroll
    for (int I = 0; I < NIT; ++I) {
        const int kb = wv + 8 * I;
        if (kb < 25) {
            int k = kb * 32 + 8 * g;
            if (k > 776) k = 776;              // in-bounds; pad-zero A covers
            const float4 lo4 = *reinterpret_cast<const float4*>(wrow + k);
            const float4 hi4 = *reinterpret_cast<const float4*>(wrow + k + 4);
            union { unsigned u[4]; short8 s; } t;
            t.u[0] = pkbf2(lo4.x, lo4.y);
            t.u[1] = pkbf2(lo4.z, lo4.w);
            t.u[2] = pkbf2(hi4.x, hi4.y);
            t.u[3] = pkbf2(hi4.z, hi4.w);
            bf[I] = t.s;
        }
    }
    const float bk = (i16 < 10) ? (fc_b[i16] - bias[i16]) : 0.f;

    auto process = [&](float4 v, unsigned im, unsigned j) {
        const unsigned y   = (j * 1171u) >> 13;       // j/7 (exact, j<196)
        const unsigned cx  = j - 7u * y;              // float4-col 0..6
        const unsigned par = y & 1u;
        const float CA = par ? C2p : C0, SA = par ? S2p : S0;
        const float CB = par ? C3  : C1, SB = par ? S3  : S1;
        float sa, ca, sb, cb;
        __sincosf(v.x, &sa, &ca);  __sincosf(v.y, &sb, &cb);
        const float za1 = CA * ca + SA * (sa * sb);
        const float zb1 = CB * (ca * cb) + SB * sb;
        __sincosf(v.z, &sa, &ca);  __sincosf(v.w, &sb, &cb);
        const float za2 = CA * ca + SA * (sa * sb);
        const float zb2 = CB * (ca * cb) + SB * sb;
        const unsigned e = im * S2 + (y >> 1) * 56u + 8u * cx + 2u * par;
        *reinterpret_cast<unsigned*>(&q_lds[e])     = pkbf2(za1, zb1);
        *reinterpret_cast<unsigned*>(&q_lds[e + 4]) = pkbf2(za2, zb2);
    };

    const unsigned img0 = (unsigned)tid / 196u;
    const unsigned jv0  = (unsigned)tid - 196u * img0;

    #pragma unroll
    for (int s = 0; s < NSLAB; ++s) {
        // -------- phase A: process the 7 prefetched units --------
        unsigned img = img0, jv = jv0;
        #pragma unroll
        for (int t = 0; t < 6; ++t) {
            process(r[t], img, jv);
            img += 2; jv += 120; if (jv >= 196) { jv -= 196; img += 1; }
        }
        if (tid < 64) process(r[6], img, jv);      // tail: u = 3072+tid

        // issue next slab's loads NOW (land during phase B + epilogue)
        if (s + 1 < NSLAB) {
            #pragma unroll
            for (int t = 0; t < 6; ++t) r[t] = xf4[ub1 + t * BLOCK + tid];
            r[6] = xf4[ub1 + 6 * BLOCK + (tid & 63)];
        }

        __syncthreads();                 // barrier A: q_lds ready
                                         // (also: wave0's prev epilogue done)

        // -------- phase B: MFMA over K --------
        f32x4 acc = {0.f, 0.f, 0.f, 0.f};
        #pragma unroll
        for (int I = 0; I < NIT; ++I) {
            const int kb = wv + 8 * I;
            if (kb < 25) {                           // wave-uniform
                const short8 a = *reinterpret_cast<const short8*>(
                    &q_lds[i16 * S2 + kb * 32 + 8 * g]);
                acc = __builtin_amdgcn_mfma_f32_16x16x32_bf16(a, bf[I], acc,
                                                              0, 0, 0);
            }
        }
        if (wv > 0)
            *reinterpret_cast<f32x4*>(&cpart[(wv - 1) * 256 + lane * 4]) = acc;

        __syncthreads();                 // barrier B: cpart ready, q reads done

        // -------- epilogue (wave0) — overlaps next slab's phase A --------
        if (wv == 0) {
            #pragma unroll
            for (int p = 0; p < 7; ++p)
                acc += *reinterpret_cast<const f32x4*>(
                    &cpart[p * 256 + lane * 4]);
            const int ibs = (s == 0) ? ib0 : ib1;
            #pragma unroll
            for (int rr = 0; rr < 4; ++rr) {
                const float lg = acc[rr] + bk;
                float mx = (i16 < 10) ? lg : -3.0e38f;
                #pragma unroll
                for (int off = 1; off < 16; off <<= 1)
                    mx = fmaxf(mx, __shfl_xor(mx, off, 64));
                float sm = (i16 < 10) ? __expf(lg - mx) : 0.f;
                #pragma unroll
                for (int off = 1; off < 16; off <<= 1)
                    sm += __shfl_xor(sm, off, 64);
                const int im = ibs + g * 4 + rr;     // C row = 4g+reg [m89]
                if (i16 < 10 && im < B)
                    out[(long)im * 10 + i16] = lg - mx - __logf(sm);
            }
        }
    }
}

extern "C" void kernel_launch(void* const* d_in, const int* in_sizes, int n_in,
                              void* d_out, int out_size, void* d_ws, size_t ws_size,
                              hipStream_t stream) {
    const float* x    = (const float*)d_in[0];
    const float* vqc  = (const float*)d_in[1];
    const float* fc_w = (const float*)d_in[2];
    const float* fc_b = (const float*)d_in[3];
    const float* bias = (const float*)d_in[4];
    float* outp = (float*)d_out;

    const int B = in_sizes[0] / 784;
    const int nblocks = (B + IMGS * NSLAB - 1) / (IMGS * NSLAB);
    hipLaunchKernelGGL(quanv_mfma, dim3(nblocks), dim3(BLOCK), 0, stream,
                       x, vqc, fc_w, fc_b, bias, outp, B);
}

// Round 9
// 17.943 us; speedup vs baseline: 1.0330x; 1.0330x over previous
//
#include <hip/hip_runtime.h>

// Fused quanvolution + FC + log_softmax via MFMA (gfx950).
// Best-measured structure (R3/R5: register-resident, q-order K, static param
// mapping) with hot-loop trims: tail masking moved to B-side zeroing at
// gather time, bf16 packing via v_cvt_pk_bf16_f32, PF=2 prefetch ring.
//
// logits[16 imgs][10] = q[16][784] @ w[784][10], mfma_f32_16x16x32_bf16.
// Lane l: i16 = l&15 (image / class), g = l>>4 (k-subgroup).
// A frag k-run = patches j0=kb*8+2g, j0+1: two float4 rows (off, off+28).
//   za = cos(pa)cos(xa) + sin(pa)sin(xa)sin(xb)   (top row -> p0,p1)
//   zb = cos(pb)cos(xa)cos(xb) + sin(pb)sin(xb)   (bottom row -> p2,p3)
// B frag: w[class][k..k+7] contiguous from global (L2-hot), bf16 regs;
// fragments with k>=784 zeroed (so A needs no masking: garbage*0 = 0).
// K split over 4 waves (kb = wv + 4I, 25 kblocks), partials via 3KB LDS.
// C frag (m89): col = lane&15, row = (lane>>4)*4 + reg.

typedef __attribute__((ext_vector_type(8))) short short8;
typedef __attribute__((ext_vector_type(4))) float f32x4;

constexpr int WAVES = 4;
constexpr int BLOCK = WAVES * 64;
constexpr int IMGS  = 16;
constexpr int NITER = 7;
constexpr int PF    = 2;              // prefetch ring depth

static __device__ __forceinline__ unsigned pkbf2(float lo, float hi) {
    unsigned r;
    asm("v_cvt_pk_bf16_f32 %0, %1, %2" : "=v"(r) : "v"(lo), "v"(hi));
    return r;                          // [15:0]=bf16(lo), [31:16]=bf16(hi)
}

__global__ __launch_bounds__(BLOCK, 4)
void quanv_mfma(const float* __restrict__ x,
                const float* __restrict__ vqc,
                const float* __restrict__ fc_w,
                const float* __restrict__ fc_b,
                const float* __restrict__ bias,
                float* __restrict__ out,
                int B)
{
    __shared__ float cpart[3][64 * 4];

    const int tid  = threadIdx.x;
    const int lane = tid & 63;
    const int wv   = tid >> 6;
    const int i16  = lane & 15;          // image (A row) / class (B col)
    const int g    = lane >> 4;          // k-subgroup

    const int imgBase = blockIdx.x * IMGS;
    const int imgLane = imgBase + i16;
    const long xb = (long)(imgLane < B ? imgLane : B - 1) * 784;
    const float* __restrict__ xpb = x + xb;

    // x float-offset of the patch-pair for iteration I (q-order K)
    auto xoff = [&](int I) -> int {
        const int kb = wv + 4 * I;
        int j0 = kb * 8 + 2 * g;
        if (j0 > 194) j0 = 0;                    // dead frags read patch 0
        const int r = j0 / 14, c = j0 - 14 * r;  // j0 even -> 16B aligned
        return 56 * r + 2 * c;
    };

    // ---- issue x loads for I=0..PF-1 first: start HBM stream immediately ----
    float4 bT[PF], bB[PF];
    #pragma unroll
    for (int I = 0; I < PF; ++I) {
        const int o = xoff(I);
        bT[I] = *reinterpret_cast<const float4*>(xpb + o);        // row 2r
        bB[I] = *reinterpret_cast<const float4*>(xpb + o + 28);   // row 2r+1
    }

    // ---- circuit params (overlap x-load latency) ----
    float S0, C0, S1, C1, S2, C2, S3, C3;
    __sincosf(vqc[0], &S0, &C0);
    __sincosf(vqc[1], &S1, &C1);
    __sincosf(vqc[2], &S2, &C2);
    __sincosf(vqc[3], &S3, &C3);

    // ---- B fragments: contiguous, L2-hot; dead (k>=784) fragments zeroed ----
    const int ncl = (i16 < 10) ? i16 : 9;        // clamped; garbage cols unread
    const float* __restrict__ wrow = fc_w + ncl * 784;
    short8 bf[NITER];
    #pragma unroll
    for (int I = 0; I < NITER; ++I) {
        const int kb = wv + 4 * I;
        if (kb < 25) {
            int k = kb * 32 + 8 * g;
            const bool dead = (k >= 784);        // only kb==24, g>=2
            if (k > 776) k = 776;                // keep loads in-bounds
            const float4 lo4 = *reinterpret_cast<const float4*>(wrow + k);
            const float4 hi4 = *reinterpret_cast<const float4*>(wrow + k + 4);
            union { unsigned u[4]; short8 s; } t;
            t.u[0] = dead ? 0u : pkbf2(lo4.x, lo4.y);
            t.u[1] = dead ? 0u : pkbf2(lo4.z, lo4.w);
            t.u[2] = dead ? 0u : pkbf2(hi4.x, hi4.y);
            t.u[3] = dead ? 0u : pkbf2(hi4.z, hi4.w);
            bf[I] = t.s;
        }
    }

    f32x4 acc = {0.f, 0.f, 0.f, 0.f};

    #pragma unroll
    for (int I = 0; I < NITER; ++I) {
        const int kb = wv + 4 * I;
        if (kb < 25) {                           // wave-uniform skip (wv>0,I=6)
            const float4 a4 = bT[I & (PF - 1)];
            const float4 b4 = bB[I & (PF - 1)];

            if (I + PF < NITER) {                // maintain PF-deep ring
                const int o = xoff(I + PF);
                bT[I & (PF - 1)] = *reinterpret_cast<const float4*>(xpb + o);
                bB[I & (PF - 1)] = *reinterpret_cast<const float4*>(xpb + o + 28);
            }

            // patch j0: top row -> (p0,p1); bottom row -> (p2,p3). No masking:
            // dead fragments have B == 0.
            float sa, ca, sb, cb, sc, cc, sd, cd;
            __sincosf(a4.x, &sa, &ca);  __sincosf(a4.y, &sb, &cb);
            __sincosf(b4.x, &sc, &cc);  __sincosf(b4.y, &sd, &cd);
            const float q0 = C0 * ca + S0 * (sa * sb);
            const float q1 = C1 * (ca * cb) + S1 * sb;
            const float q2 = C2 * cc + S2 * (sc * sd);
            const float q3 = C3 * (cc * cd) + S3 * sd;
            // patch j0+1
            __sincosf(a4.z, &sa, &ca);  __sincosf(a4.w, &sb, &cb);
            __sincosf(b4.z, &sc, &cc);  __sincosf(b4.w, &sd, &cd);
            const float q4 = C0 * ca + S0 * (sa * sb);
            const float q5 = C1 * (ca * cb) + S1 * sb;
            const float q6 = C2 * cc + S2 * (sc * sd);
            const float q7 = C3 * (cc * cd) + S3 * sd;

            union { unsigned u[4]; short8 s; } a;
            a.u[0] = pkbf2(q0, q1);
            a.u[1] = pkbf2(q2, q3);
            a.u[2] = pkbf2(q4, q5);
            a.u[3] = pkbf2(q6, q7);

            acc = __builtin_amdgcn_mfma_f32_16x16x32_bf16(a.s, bf[I], acc,
                                                          0, 0, 0);
        }
    }

    // ---- K-split combine through LDS ----
    if (wv > 0)
        *reinterpret_cast<f32x4*>(&cpart[wv - 1][lane * 4]) = acc;
    __syncthreads();

    if (wv == 0) {
        #pragma unroll
        for (int p = 0; p < 3; ++p)
            acc += *reinterpret_cast<const f32x4*>(&cpart[p][lane * 4]);
        const float bk = (i16 < 10) ? (fc_b[i16] - bias[i16]) : 0.f;

        #pragma unroll
        for (int r = 0; r < 4; ++r) {
            const float lg = acc[r] + bk;
            float mx = (i16 < 10) ? lg : -3.0e38f;
            #pragma unroll
            for (int off = 1; off < 16; off <<= 1)
                mx = fmaxf(mx, __shfl_xor(mx, off, 64));
            float s = (i16 < 10) ? __expf(lg - mx) : 0.f;
            #pragma unroll
            for (int off = 1; off < 16; off <<= 1)
                s += __shfl_xor(s, off, 64);
            const int im = imgBase + g * 4 + r;      // C row = g*4 + reg [m89]
            if (i16 < 10 && im < B)
                out[(long)im * 10 + i16] = lg - mx - __logf(s);
        }
    }
}

extern "C" void kernel_launch(void* const* d_in, const int* in_sizes, int n_in,
                              void* d_out, int out_size, void* d_ws, size_t ws_size,
                              hipStream_t stream) {
    const float* x    = (const float*)d_in[0];
    const float* vqc  = (const float*)d_in[1];
    const float* fc_w = (const float*)d_in[2];
    const float* fc_b = (const float*)d_in[3];
    const float* bias = (const float*)d_in[4];
    float* outp = (float*)d_out;

    const int B = in_sizes[0] / 784;
    const int nblocks = (B + IMGS - 1) / IMGS;
    hipLaunchKernelGGL(quanv_mfma, dim3(nblocks), dim3(BLOCK), 0, stream,
                       x, vqc, fc_w, fc_b, bias, outp, B);
}